// Round 3
// baseline (76.376 us; speedup 1.0000x reference)
//
#include <hip/hip_runtime.h>
#include <hip/hip_bf16.h>

#define CDIM   64
#define HWDIM  4096
#define NCODES 1024
#define NELEM  8388608   // 32*64*64*64 = N*C
#define NBLOCK 1024      // vq_main grid: 131072 rows / 128 rows-per-block

typedef short bf16x8 __attribute__((ext_vector_type(8)));
typedef float f32x4  __attribute__((ext_vector_type(4)));

__device__ __forceinline__ unsigned short f2bf(float f) {
    union { float f; unsigned u; } v; v.f = f;
    unsigned r = v.u + 0x7fffu + ((v.u >> 16) & 1u);   // round-to-nearest-even
    return (unsigned short)(r >> 16);
}
__device__ __forceinline__ unsigned asu(float f) {
    union { float f; unsigned u; } v; v.f = f; return v.u;
}
__device__ __forceinline__ float asf(unsigned u) {
    union { unsigned u; float f; } v; v.u = u; return v.f;
}

// Precompute bf16 codebook + (-0.5*||e_k||^2) bias (MFMA C-operand).
__global__ void vq_prep(const float* __restrict__ E,
                        unsigned short* __restrict__ Eb,
                        float* __restrict__ bias05) {
    int t = blockIdx.x * blockDim.x + threadIdx.x;   // one thread per code
    if (t < NCODES) {
        float s = 0.f;
        #pragma unroll 8
        for (int c = 0; c < CDIM; ++c) {
            float v = E[t * CDIM + c];
            Eb[t * CDIM + c] = f2bf(v);
            s = fmaf(v, v, s);
        }
        bias05[t] = -0.5f * s;
    }
}

// Wave pair shares 64 rows; each wave scans 512 codes (half the codebook).
// score = z.e - 0.5||e||^2 (bias folded into MFMA C); argmax via packed keys
// (code index in low 10 mantissa bits, single v_and_or + v_max per element).
__global__ __launch_bounds__(256, 4)
void vq_main(const float* __restrict__ z,
             const float* __restrict__ E,
             const unsigned short* __restrict__ Eb,
             const float* __restrict__ bias05,
             float* __restrict__ out,
             float* __restrict__ partial) {
    const int lane = threadIdx.x & 63;
    const int wave = threadIdx.x >> 6;
    const int pair = wave >> 1;    // 0..1 : which 64-row group of the block
    const int half = wave & 1;     // 0..1 : which 512-code half
    const int lrow = lane & 15;    // row/code-col within 16-tile
    const int lgrp = lane >> 4;    // k-group 0..3

    const int n0 = blockIdx.x * 128 + pair * 64;  // pair's first flat row
    const int b  = n0 >> 12;
    const int hw = n0 & 4095;                      // 128-aligned; +63 in batch
    const float* zb   = z   + (size_t)b * (CDIM * HWDIM);
    float*       outb = out + (size_t)b * (CDIM * HWDIM);

    // A fragments: tile t rows n0+16t..+15. lane holds A[lrow][k=32s+8g+j].
    float szz = 0.f;
    bf16x8 afrag[4][2];
    #pragma unroll
    for (int t = 0; t < 4; ++t)
        #pragma unroll
        for (int s = 0; s < 2; ++s)
            #pragma unroll
            for (int j = 0; j < 8; ++j) {
                int c = 32 * s + 8 * lgrp + j;
                float v = zb[c * HWDIM + hw + t * 16 + lrow];
                szz = fmaf(v, v, szz);
                afrag[t][s][j] = (short)f2bf(v);
            }

    // running packed keys (score with code in low 10 bits), argmax
    float run[4][4];
    #pragma unroll
    for (int t = 0; t < 4; ++t)
        #pragma unroll
        for (int r = 0; r < 4; ++r) run[t][r] = -3.0e38f;

    const int cbase = half * 512;

    // depth-2 software prefetch of B fragments + bias (static reg names)
    bf16x8 cb0A, cb1A, cb0B, cb1B;
    float  bvA, bvB;
    {
        int c0 = cbase + lrow;
        int c1 = cbase + 16 + lrow;
        cb0A = *(const bf16x8*)(Eb + c0 * CDIM      + 8 * lgrp);
        cb1A = *(const bf16x8*)(Eb + c0 * CDIM + 32 + 8 * lgrp);
        cb0B = *(const bf16x8*)(Eb + c1 * CDIM      + 8 * lgrp);
        cb1B = *(const bf16x8*)(Eb + c1 * CDIM + 32 + 8 * lgrp);
        bvA = bias05[c0];
        bvB = bias05[c1];
    }

    for (int kt = 0; kt < 32; kt += 2) {
        // even step
        {
            bf16x8 b0 = cb0A, b1 = cb1A; float bv = bvA;
            if (kt + 2 < 32) {
                int c = cbase + (kt + 2) * 16 + lrow;
                cb0A = *(const bf16x8*)(Eb + c * CDIM      + 8 * lgrp);
                cb1A = *(const bf16x8*)(Eb + c * CDIM + 32 + 8 * lgrp);
                bvA  = bias05[c];
            }
            const unsigned code = (unsigned)(cbase + kt * 16 + lrow);
            f32x4 cinit = {bv, bv, bv, bv};
            #pragma unroll
            for (int t = 0; t < 4; ++t) {
                f32x4 acc = __builtin_amdgcn_mfma_f32_16x16x32_bf16(afrag[t][0], b0, cinit, 0, 0, 0);
                acc = __builtin_amdgcn_mfma_f32_16x16x32_bf16(afrag[t][1], b1, acc, 0, 0, 0);
                #pragma unroll
                for (int r = 0; r < 4; ++r) {
                    float key = asf((asu(acc[r]) & 0xFFFFFC00u) | code); // v_and_or_b32
                    run[t][r] = fmaxf(run[t][r], key);
                }
            }
        }
        // odd step
        {
            bf16x8 b0 = cb0B, b1 = cb1B; float bv = bvB;
            if (kt + 3 < 32) {
                int c = cbase + (kt + 3) * 16 + lrow;
                cb0B = *(const bf16x8*)(Eb + c * CDIM      + 8 * lgrp);
                cb1B = *(const bf16x8*)(Eb + c * CDIM + 32 + 8 * lgrp);
                bvB  = bias05[c];
            }
            const unsigned code = (unsigned)(cbase + (kt + 1) * 16 + lrow);
            f32x4 cinit = {bv, bv, bv, bv};
            #pragma unroll
            for (int t = 0; t < 4; ++t) {
                f32x4 acc = __builtin_amdgcn_mfma_f32_16x16x32_bf16(afrag[t][0], b0, cinit, 0, 0, 0);
                acc = __builtin_amdgcn_mfma_f32_16x16x32_bf16(afrag[t][1], b1, acc, 0, 0, 0);
                #pragma unroll
                for (int r = 0; r < 4; ++r) {
                    float key = asf((asu(acc[r]) & 0xFFFFFC00u) | code);
                    run[t][r] = fmaxf(run[t][r], key);
                }
            }
        }
    }

    // reduce packed keys across the 16 code-columns (lrow lanes): pure max
    #pragma unroll
    for (int m = 1; m <= 8; m <<= 1)
        #pragma unroll
        for (int t = 0; t < 4; ++t)
            #pragma unroll
            for (int r = 0; r < 4; ++r)
                run[t][r] = fmaxf(run[t][r], __shfl_xor(run[t][r], m, 64));

    // publish per-row half-codebook winners; merge halves via max
    __shared__ float skey[2][64][2];
    __shared__ float lpart[4];
    if (lrow == 0) {
        #pragma unroll
        for (int t = 0; t < 4; ++t)
            #pragma unroll
            for (int r = 0; r < 4; ++r)
                skey[pair][t * 16 + 4 * lgrp + r][half] = run[t][r];
    }
    __syncthreads();

    // epilogue: wave handles tiles {2*half, 2*half+1} of its pair (32 rows)
    float dsum = 0.f;
    #pragma unroll
    for (int u = 0; u < 2; ++u) {
        const int tt  = 2 * half + u;
        const int row = tt * 16 + lrow;
        float km = fmaxf(skey[pair][row][0], skey[pair][row][1]);
        const int code = (int)(asu(km) & 1023u);
        if (lgrp == 0) dsum = fmaf(-2.f, km, dsum);   // d_min = -2*score
        const f32x4* ep  = (const f32x4*)(E + code * CDIM      + 8 * lgrp);
        const f32x4* ep2 = (const f32x4*)(E + code * CDIM + 32 + 8 * lgrp);
        f32x4 qa = ep[0], qb = ep[1], qc = ep2[0], qd = ep2[1];
        float* ob = outb + hw + tt * 16 + lrow;
        #pragma unroll
        for (int j = 0; j < 4; ++j) {
            ob[(8 * lgrp + j)          * HWDIM] = qa[j];
            ob[(8 * lgrp + 4 + j)      * HWDIM] = qb[j];
            ob[(32 + 8 * lgrp + j)     * HWDIM] = qc[j];
            ob[(32 + 8 * lgrp + 4 + j) * HWDIM] = qd[j];
        }
    }

    // loss partial: sum z^2 (once per pair: half==0 wave) + sum d_min
    float contrib = (half == 0 ? szz : 0.f) + dsum;
    #pragma unroll
    for (int m = 32; m >= 1; m >>= 1) contrib += __shfl_xor(contrib, m, 64);
    if (lane == 0) lpart[wave] = contrib;
    __syncthreads();
    if (threadIdx.x == 0)
        partial[blockIdx.x] = lpart[0] + lpart[1] + lpart[2] + lpart[3];
}

__global__ void vq_fin(const float* __restrict__ partial,
                       float* __restrict__ out) {
    int lane = threadIdx.x;
    float s = 0.f;
    for (int i = lane; i < NBLOCK; i += 64) s += partial[i];
    #pragma unroll
    for (int m = 32; m >= 1; m >>= 1) s += __shfl_xor(s, m, 64);
    if (lane == 0) out[NELEM] = 1.25f * s / (float)NELEM;
}

extern "C" void kernel_launch(void* const* d_in, const int* in_sizes, int n_in,
                              void* d_out, int out_size, void* d_ws, size_t ws_size,
                              hipStream_t stream) {
    const float* z = (const float*)d_in[0];
    const float* E = (const float*)d_in[1];
    float* out = (float*)d_out;

    unsigned short* Eb = (unsigned short*)d_ws;                    // 128 KB
    float* bias05      = (float*)((char*)d_ws + 131072);           // 4 KB
    float* partial     = (float*)((char*)d_ws + 131072 + 4096);    // 4 KB

    vq_prep<<<4, 256, 0, stream>>>(E, Eb, bias05);
    vq_main<<<NBLOCK, 256, 0, stream>>>(z, E, Eb, bias05, out, partial);
    vq_fin<<<1, 64, 0, stream>>>(partial, out);
}

// Round 4
// 61.220 us; speedup vs baseline: 1.2476x; 1.2476x over previous
//
#include <hip/hip_runtime.h>
#include <hip/hip_bf16.h>

#define CDIM   64
#define HWDIM  4096
#define NCODES 1024
#define NELEM  8388608   // 32*64*64*64 = N*C
#define NBLOCK 2048      // vq_main grid: 131072 rows / 64 rows-per-block(wave)

typedef short bf16x8 __attribute__((ext_vector_type(8)));
typedef float f32x4  __attribute__((ext_vector_type(4)));

__device__ __forceinline__ unsigned short f2bf(float f) {
    union { float f; unsigned u; } v; v.f = f;
    unsigned r = v.u + 0x7fffu + ((v.u >> 16) & 1u);   // round-to-nearest-even
    return (unsigned short)(r >> 16);
}
__device__ __forceinline__ unsigned asu(float f) {
    union { float f; unsigned u; } v; v.f = f; return v.u;
}
__device__ __forceinline__ float asf(unsigned u) {
    union { unsigned u; float f; } v; v.u = u; return v.f;
}

// Precompute bf16 codebook + (-0.5*||e_k||^2) bias (MFMA C-operand).
__global__ void vq_prep(const float* __restrict__ E,
                        unsigned short* __restrict__ Eb,
                        float* __restrict__ bias05) {
    int t = blockIdx.x * blockDim.x + threadIdx.x;   // one thread per code
    if (t < NCODES) {
        float s = 0.f;
        #pragma unroll 8
        for (int c = 0; c < CDIM; ++c) {
            float v = E[t * CDIM + c];
            Eb[t * CDIM + c] = f2bf(v);
            s = fmaf(v, v, s);
        }
        bias05[t] = -0.5f * s;
    }
}

// One wave (= one block) owns 64 rows x the FULL 1024-code codebook.
// score = z.e - 0.5||e||^2 (bias folded into MFMA C-init); argmax over packed
// keys (code index in low 10 mantissa bits -> single v_and_or + v_max).
__global__ __launch_bounds__(64)
void vq_main(const float* __restrict__ z,
             const float* __restrict__ E,
             const unsigned short* __restrict__ Eb,
             const float* __restrict__ bias05,
             float* __restrict__ out,
             float* __restrict__ partial) {
    const int lane = threadIdx.x;   // 0..63
    const int lrow = lane & 15;     // row/code-col within 16-tile
    const int lgrp = lane >> 4;     // k-group 0..3

    const int n0 = blockIdx.x * 64;    // wave's first flat row (b*4096 + hw)
    const int b  = n0 >> 12;
    const int hw = n0 & 4095;          // 64-aligned; +63 stays in batch
    const float* zb   = z   + (size_t)b * (CDIM * HWDIM);
    float*       outb = out + (size_t)b * (CDIM * HWDIM);

    // A fragments: tile t rows n0+16t..+15. lane holds A[lrow][k=32s+8g+j].
    float szz = 0.f;
    bf16x8 afrag[4][2];
    #pragma unroll
    for (int t = 0; t < 4; ++t)
        #pragma unroll
        for (int s = 0; s < 2; ++s)
            #pragma unroll
            for (int j = 0; j < 8; ++j) {
                int c = 32 * s + 8 * lgrp + j;
                float v = zb[c * HWDIM + hw + t * 16 + lrow];
                szz = fmaf(v, v, szz);
                afrag[t][s][j] = (short)f2bf(v);
            }

    // running packed keys (score with code idx in low 10 bits), argmax
    float run[4][4];
    #pragma unroll
    for (int t = 0; t < 4; ++t)
        #pragma unroll
        for (int r = 0; r < 4; ++r) run[t][r] = -3.0e38f;

    // depth-2 software prefetch of B fragments + bias (static reg names)
    bf16x8 cb0A, cb1A, cb0B, cb1B;
    float  bvA, bvB;
    {
        int c0 = lrow;            // kt=0
        int c1 = 16 + lrow;       // kt=1
        cb0A = *(const bf16x8*)(Eb + c0 * CDIM      + 8 * lgrp);
        cb1A = *(const bf16x8*)(Eb + c0 * CDIM + 32 + 8 * lgrp);
        cb0B = *(const bf16x8*)(Eb + c1 * CDIM      + 8 * lgrp);
        cb1B = *(const bf16x8*)(Eb + c1 * CDIM + 32 + 8 * lgrp);
        bvA = bias05[c0];
        bvB = bias05[c1];
    }

    for (int kt = 0; kt < 64; kt += 2) {
        // even step
        {
            bf16x8 b0 = cb0A, b1 = cb1A; float bv = bvA;
            if (kt + 2 < 64) {
                int c = (kt + 2) * 16 + lrow;
                cb0A = *(const bf16x8*)(Eb + c * CDIM      + 8 * lgrp);
                cb1A = *(const bf16x8*)(Eb + c * CDIM + 32 + 8 * lgrp);
                bvA  = bias05[c];
            }
            const unsigned code = (unsigned)(kt * 16 + lrow);
            f32x4 cinit = {bv, bv, bv, bv};
            #pragma unroll
            for (int t = 0; t < 4; ++t) {
                f32x4 acc = __builtin_amdgcn_mfma_f32_16x16x32_bf16(afrag[t][0], b0, cinit, 0, 0, 0);
                acc = __builtin_amdgcn_mfma_f32_16x16x32_bf16(afrag[t][1], b1, acc, 0, 0, 0);
                #pragma unroll
                for (int r = 0; r < 4; ++r) {
                    float key = asf((asu(acc[r]) & 0xFFFFFC00u) | code); // v_and_or_b32
                    run[t][r] = fmaxf(run[t][r], key);
                }
            }
        }
        // odd step
        {
            bf16x8 b0 = cb0B, b1 = cb1B; float bv = bvB;
            if (kt + 3 < 64) {
                int c = (kt + 3) * 16 + lrow;
                cb0B = *(const bf16x8*)(Eb + c * CDIM      + 8 * lgrp);
                cb1B = *(const bf16x8*)(Eb + c * CDIM + 32 + 8 * lgrp);
                bvB  = bias05[c];
            }
            const unsigned code = (unsigned)((kt + 1) * 16 + lrow);
            f32x4 cinit = {bv, bv, bv, bv};
            #pragma unroll
            for (int t = 0; t < 4; ++t) {
                f32x4 acc = __builtin_amdgcn_mfma_f32_16x16x32_bf16(afrag[t][0], b0, cinit, 0, 0, 0);
                acc = __builtin_amdgcn_mfma_f32_16x16x32_bf16(afrag[t][1], b1, acc, 0, 0, 0);
                #pragma unroll
                for (int r = 0; r < 4; ++r) {
                    float key = asf((asu(acc[r]) & 0xFFFFFC00u) | code);
                    run[t][r] = fmaxf(run[t][r], key);
                }
            }
        }
    }

    // reduce packed keys across the 16 code-columns (lrow lanes): pure max
    #pragma unroll
    for (int m = 1; m <= 8; m <<= 1)
        #pragma unroll
        for (int t = 0; t < 4; ++t)
            #pragma unroll
            for (int r = 0; r < 4; ++r)
                run[t][r] = fmaxf(run[t][r], __shfl_xor(run[t][r], m, 64));

    // publish per-row argmin code: lane group g holds rows 4g+r of each tile
    __shared__ int sidx[64];
    if (lrow == 0) {
        #pragma unroll
        for (int t = 0; t < 4; ++t)
            #pragma unroll
            for (int r = 0; r < 4; ++r)
                sidx[t * 16 + 4 * lgrp + r] = (int)(asu(run[t][r]) & 1023u);
    }
    __syncthreads();

    // epilogue: gather fp32 codebook rows, write transposed out (R2 pattern)
    #pragma unroll
    for (int t = 0; t < 4; ++t) {
        const int idxr = sidx[t * 16 + lrow];
        const f32x4* ep  = (const f32x4*)(E + idxr * CDIM      + 8 * lgrp);
        const f32x4* ep2 = (const f32x4*)(E + idxr * CDIM + 32 + 8 * lgrp);
        f32x4 qa = ep[0], qb = ep[1], qc = ep2[0], qd = ep2[1];
        float* ob = outb + hw + t * 16 + lrow;
        #pragma unroll
        for (int j = 0; j < 4; ++j) {
            ob[(8 * lgrp + j)          * HWDIM] = qa[j];
            ob[(8 * lgrp + 4 + j)      * HWDIM] = qb[j];
            ob[(32 + 8 * lgrp + j)     * HWDIM] = qc[j];
            ob[(32 + 8 * lgrp + 4 + j) * HWDIM] = qd[j];
        }
    }

    // loss partial: sum z^2 + sum over rows of d_min (= -2 * packed score)
    float dsum = 0.f;
    #pragma unroll
    for (int t = 0; t < 4; ++t)
        #pragma unroll
        for (int r = 0; r < 4; ++r) dsum += run[t][r];
    float contrib = szz + ((lrow == 0) ? (-2.f * dsum) : 0.f);
    #pragma unroll
    for (int m = 32; m >= 1; m >>= 1) contrib += __shfl_xor(contrib, m, 64);
    if (lane == 0) partial[blockIdx.x] = contrib;
}

__global__ void vq_fin(const float* __restrict__ partial,
                       float* __restrict__ out) {
    int lane = threadIdx.x;   // 64 threads
    float s = 0.f;
    for (int i = lane; i < NBLOCK; i += 64) s += partial[i];
    #pragma unroll
    for (int m = 32; m >= 1; m >>= 1) s += __shfl_xor(s, m, 64);
    if (lane == 0) out[NELEM] = 1.25f * s / (float)NELEM;
}

extern "C" void kernel_launch(void* const* d_in, const int* in_sizes, int n_in,
                              void* d_out, int out_size, void* d_ws, size_t ws_size,
                              hipStream_t stream) {
    const float* z = (const float*)d_in[0];
    const float* E = (const float*)d_in[1];
    float* out = (float*)d_out;

    unsigned short* Eb = (unsigned short*)d_ws;                    // 128 KB
    float* bias05      = (float*)((char*)d_ws + 131072);           // 4 KB
    float* partial     = (float*)((char*)d_ws + 131072 + 4096);    // 8 KB

    vq_prep<<<4, 256, 0, stream>>>(E, Eb, bias05);
    vq_main<<<NBLOCK, 64, 0, stream>>>(z, E, Eb, bias05, out, partial);
    vq_fin<<<1, 64, 0, stream>>>(partial, out);
}